// Round 1
// baseline (205.363 us; speedup 1.0000x reference)
//
#include <hip/hip_runtime.h>
#include <stdint.h>

// Toeplitz matvec out[b,k,e] = sum_j T[k,j] x[b,j,e], T from pos/zero/neg.
// B=8, N=2048, E=1024. Implemented as batched bf16 MFMA GEMM:
//   ws[0..8MiB)   : T   bf16 [2048][2048] row-major (k-major, j contiguous)
//   ws[8..40MiB)  : xT  bf16 [8][1024][2048]  (e-major, j contiguous) = "B^T" form
// Both operands k-contiguous -> all LDS fragment reads are ds_read_b128 on a
// +8-ushort padded stride (144B row -> 2-way max bank aliasing, free per m136).

#define B_  8
#define N_  2048
#define E_  1024

typedef __bf16 bf16x8 __attribute__((ext_vector_type(8)));
typedef float  f32x4  __attribute__((ext_vector_type(4)));

__device__ __forceinline__ unsigned short f32_to_bf16_rne(float f) {
    union { float f; unsigned int u; } cv; cv.f = f;
    unsigned int u = cv.u;
    u += 0x7fffu + ((u >> 16) & 1u);   // round-to-nearest-even (inputs are normal floats)
    return (unsigned short)(u >> 16);
}

// ---------------- T materialization: 2048x2048 bf16, 8 elems/thread ----------
__global__ __launch_bounds__(256) void build_T(const float* __restrict__ pos,
                                               const float* __restrict__ zero,
                                               const float* __restrict__ neg,
                                               unsigned short* __restrict__ T) {
    int t  = blockIdx.x * 256 + threadIdx.x;   // 0 .. 2048*256-1
    int k  = t >> 8;                           // row
    int j0 = (t & 255) * 8;                    // 8 consecutive cols
    float zv = zero[0];
    union { unsigned short s[8]; uint4 v; } pk;
#pragma unroll
    for (int i = 0; i < 8; ++i) {
        int j = j0 + i;
        float v = (j < k) ? pos[k - j - 1]
                : (j == k) ? zv
                : neg[N_ - 1 - j + k];
        pk.s[i] = f32_to_bf16_rne(v);
    }
    *(uint4*)(T + (size_t)k * N_ + j0) = pk.v;
}

// ---------------- x [b][j][e] fp32 -> xT [b][e][j] bf16, 64x64 LDS tiles -----
__global__ __launch_bounds__(256) void transpose_x(const float* __restrict__ x,
                                                   unsigned short* __restrict__ xT) {
    // stride 66: phase-1 scalar-write lane delta = 4*66 = 264 words == 8 mod 32
    // -> 4-way; phase-2 float2 reads 8B-aligned (66 even), 2-way.
    __shared__ float tile[64][66];
    int b  = blockIdx.z;
    int j0 = blockIdx.y * 64;
    int e0 = blockIdx.x * 64;
    int t  = threadIdx.x;

    int e4 = t & 15, jr = t >> 4;
#pragma unroll
    for (int it = 0; it < 4; ++it) {
        int j = jr + it * 16;
        const float4 v = *(const float4*)(x + ((size_t)(b * N_ + j0 + j) * E_) + e0 + e4 * 4);
        tile[e4 * 4 + 0][j] = v.x;
        tile[e4 * 4 + 1][j] = v.y;
        tile[e4 * 4 + 2][j] = v.z;
        tile[e4 * 4 + 3][j] = v.w;
    }
    __syncthreads();
    int j2 = (t & 31) * 2, er = t >> 5;
#pragma unroll
    for (int it = 0; it < 8; ++it) {
        int e = er + it * 8;
        float2 v = *(const float2*)&tile[e][j2];
        union { unsigned short s[2]; unsigned int u; } pk;
        pk.s[0] = f32_to_bf16_rne(v.x);
        pk.s[1] = f32_to_bf16_rne(v.y);
        *(unsigned int*)(xT + ((size_t)(b * E_ + e0 + e)) * N_ + j0 + j2) = pk.u;
    }
}

// ---------------- main GEMM: per batch  out_b[2048x1024] = T . x_b ----------
// 128x128 C-tile, BK=64, 256 thr = 4 waves in 2x2, each wave 64x64 via 4x4
// mfma_f32_16x16x32_bf16. A-frag: m=lane&15, k=quad*8+j (k contiguous).
// B-frag: n=lane&15, k=quad*8+j -> needs [n][k] storage = xT rows. C/D:
// col=lane&15, row=quad*4+reg (verified m89/m91).
#define BK  64
#define LDT 72   // padded LDS row stride (ushorts): 144 B, 16B-aligned

__global__ __launch_bounds__(256) void gemm_toep(const unsigned short* __restrict__ T,
                                                 const unsigned short* __restrict__ xT,
                                                 float* __restrict__ out) {
    __shared__ __align__(16) unsigned short As[128 * LDT];
    __shared__ __align__(16) unsigned short Bs[128 * LDT];

    int bid = blockIdx.x;            // (b, mt, nt): nt fastest -> T rows + x_b slab L2-resident
    int b   = bid >> 7;
    int mt  = (bid >> 3) & 15;
    int nt  = bid & 7;
    int m0  = mt * 128, n0 = nt * 128;

    int t    = threadIdx.x;
    int lane = t & 63;
    int w    = t >> 6;
    int wr   = w >> 1, wc = w & 1;
    int lm   = lane & 15, quad = lane >> 4;

    const unsigned short* Ag = T + (size_t)m0 * N_;
    const unsigned short* Bg = xT + (size_t)(b * E_ + n0) * N_;

    int srow = t >> 3;           // 0..31, staging row
    int scol = (t & 7) * 8;      // 0..56, staging col (8 bf16 = 16 B)

    f32x4 acc[4][4] = {};

    for (int kt = 0; kt < N_ / BK; ++kt) {
        int kbase = kt * BK;
        __syncthreads();
#pragma unroll
        for (int it = 0; it < 4; ++it) {
            int r = srow + it * 32;
            uint4 av = *(const uint4*)(Ag + (size_t)r * N_ + kbase + scol);
            uint4 bv = *(const uint4*)(Bg + (size_t)r * N_ + kbase + scol);
            *(uint4*)(As + r * LDT + scol) = av;
            *(uint4*)(Bs + r * LDT + scol) = bv;
        }
        __syncthreads();
#pragma unroll
        for (int kh = 0; kh < 2; ++kh) {
            int ko = kh * 32;
            bf16x8 af[4], bfr[4];
#pragma unroll
            for (int i = 0; i < 4; ++i) {
                af[i]  = *(const bf16x8*)(As + (wr * 64 + i * 16 + lm) * LDT + ko + quad * 8);
                bfr[i] = *(const bf16x8*)(Bs + (wc * 64 + i * 16 + lm) * LDT + ko + quad * 8);
            }
#pragma unroll
            for (int i = 0; i < 4; ++i)
#pragma unroll
                for (int jn = 0; jn < 4; ++jn)
                    acc[i][jn] = __builtin_amdgcn_mfma_f32_16x16x32_bf16(af[i], bfr[jn], acc[i][jn], 0, 0, 0);
        }
    }

    float* Og = out + ((size_t)(b * N_ + m0)) * E_ + n0;
#pragma unroll
    for (int i = 0; i < 4; ++i) {
#pragma unroll
        for (int jn = 0; jn < 4; ++jn) {
            int e = wc * 64 + jn * 16 + lm;
#pragma unroll
            for (int r = 0; r < 4; ++r) {
                int k = wr * 64 + i * 16 + quad * 4 + r;
                Og[(size_t)k * E_ + e] = acc[i][jn][r];
            }
        }
    }
}

// ---------------- fallback (ws too small): direct fp32 dot ------------------
__global__ __launch_bounds__(256) void naive_toep(const float* __restrict__ x,
                                                  const float* __restrict__ pos,
                                                  const float* __restrict__ zero,
                                                  const float* __restrict__ neg,
                                                  float* __restrict__ out) {
    int bid = blockIdx.x;
    int e   = (bid & 3) * 256 + threadIdx.x;
    int k   = (bid >> 2) & (N_ - 1);
    int b   = bid >> 13;
    float zv = zero[0];
    float acc = 0.f;
    const float* xb = x + (size_t)b * N_ * E_ + e;
    for (int j = 0; j < N_; ++j) {
        float c = (j < k) ? pos[k - j - 1] : (j == k) ? zv : neg[N_ - 1 - j + k];
        acc += c * xb[(size_t)j * E_];
    }
    out[((size_t)(b * N_ + k)) * E_ + e] = acc;
}

extern "C" void kernel_launch(void* const* d_in, const int* in_sizes, int n_in,
                              void* d_out, int out_size, void* d_ws, size_t ws_size,
                              hipStream_t stream) {
    const float* x    = (const float*)d_in[0];
    const float* pos  = (const float*)d_in[1];
    const float* zero = (const float*)d_in[2];
    const float* neg  = (const float*)d_in[3];
    float* out = (float*)d_out;

    const size_t needT = (size_t)N_ * N_ * sizeof(unsigned short);          // 8 MiB
    const size_t needX = (size_t)B_ * E_ * N_ * sizeof(unsigned short);     // 32 MiB
    if (ws_size >= needT + needX) {
        unsigned short* T  = (unsigned short*)d_ws;
        unsigned short* xT = (unsigned short*)d_ws + (size_t)N_ * N_;
        build_T<<<2048, 256, 0, stream>>>(pos, zero, neg, T);
        transpose_x<<<dim3(16, 32, 8), 256, 0, stream>>>(x, xT);
        gemm_toep<<<1024, 256, 0, stream>>>(T, xT, out);
    } else {
        naive_toep<<<65536, 256, 0, stream>>>(x, pos, zero, neg, out);
    }
}

// Round 2
// 199.579 us; speedup vs baseline: 1.0290x; 1.0290x over previous
//
#include <hip/hip_runtime.h>
#include <stdint.h>

// Toeplitz matvec out[b,k,e] = sum_j T[k,j] x[b,j,e], T from pos/zero/neg.
// B=8, N=2048, E=1024. Batched bf16 MFMA GEMM (m97-style):
//   ws[0..8MiB)   : T   bf16 [2048][2048] row-major (j contiguous)
//   ws[8..40MiB)  : xT  bf16 [8][1024][2048]  (e-major, j contiguous)
// GEMM stages via global_load_lds width=16 into UNPADDED [128][64] LDS tiles
// (m104: landing = wave-uniform base + lane*16 -> no padding allowed).
// Bank conflicts on ds_read_b128 fragments are killed by XOR-swizzling the
// 16B col-block on the GLOBAL pointer: block c lands at c^(row&7); fragment
// reads un-swizzle -> lm lanes spread over all 32 banks (2-way = free, m136).

#define B_  8
#define N_  2048
#define E_  1024

typedef __bf16 bf16x8 __attribute__((ext_vector_type(8)));
typedef float  f32x4  __attribute__((ext_vector_type(4)));

__device__ __forceinline__ unsigned short f32_to_bf16_rne(float f) {
    union { float f; unsigned int u; } cv; cv.f = f;
    unsigned int u = cv.u;
    u += 0x7fffu + ((u >> 16) & 1u);
    return (unsigned short)(u >> 16);
}

__device__ __forceinline__ void async_copy16(const unsigned short* g, unsigned short* l) {
    __builtin_amdgcn_global_load_lds((const __attribute__((address_space(1))) void*)g,
                                     (__attribute__((address_space(3))) void*)l,
                                     16, 0, 0);
}

// ---------------- T materialization: 2048x2048 bf16, 8 elems/thread ----------
__global__ __launch_bounds__(256) void build_T(const float* __restrict__ pos,
                                               const float* __restrict__ zero,
                                               const float* __restrict__ neg,
                                               unsigned short* __restrict__ T) {
    int t  = blockIdx.x * 256 + threadIdx.x;
    int k  = t >> 8;
    int j0 = (t & 255) * 8;
    float zv = zero[0];
    union { unsigned short s[8]; uint4 v; } pk;
#pragma unroll
    for (int i = 0; i < 8; ++i) {
        int j = j0 + i;
        float v = (j < k) ? pos[k - j - 1]
                : (j == k) ? zv
                : neg[N_ - 1 - j + k];
        pk.s[i] = f32_to_bf16_rne(v);
    }
    *(uint4*)(T + (size_t)k * N_ + j0) = pk.v;
}

// ---------------- x [b][j][e] fp32 -> xT [b][e][j] bf16, 64x64 LDS tiles -----
__global__ __launch_bounds__(256) void transpose_x(const float* __restrict__ x,
                                                   unsigned short* __restrict__ xT) {
    __shared__ float tile[64][66];
    int b  = blockIdx.z;
    int j0 = blockIdx.y * 64;
    int e0 = blockIdx.x * 64;
    int t  = threadIdx.x;

    int e4 = t & 15, jr = t >> 4;
#pragma unroll
    for (int it = 0; it < 4; ++it) {
        int j = jr + it * 16;
        const float4 v = *(const float4*)(x + ((size_t)(b * N_ + j0 + j) * E_) + e0 + e4 * 4);
        tile[e4 * 4 + 0][j] = v.x;
        tile[e4 * 4 + 1][j] = v.y;
        tile[e4 * 4 + 2][j] = v.z;
        tile[e4 * 4 + 3][j] = v.w;
    }
    __syncthreads();
    int j2 = (t & 31) * 2, er = t >> 5;
#pragma unroll
    for (int it = 0; it < 8; ++it) {
        int e = er + it * 8;
        float2 v = *(const float2*)&tile[e][j2];
        union { unsigned short s[2]; unsigned int u; } pk;
        pk.s[0] = f32_to_bf16_rne(v.x);
        pk.s[1] = f32_to_bf16_rne(v.y);
        *(unsigned int*)(xT + ((size_t)(b * E_ + e0 + e)) * N_ + j0 + j2) = pk.u;
    }
}

// ---------------- main GEMM: per batch  out_b[2048x1024] = T . x_b ----------
// 128x128 C-tile, BK=64, 4 waves 2x2, each wave 64x64 via 4x4 of
// mfma_f32_16x16x32_bf16. A/B frags: lane m(n)=lane&15, k=quad*8+j.
// C/D: col=lane&15, row=quad*4+reg (m89/m91).
__global__ __launch_bounds__(256) void gemm_toep(const unsigned short* __restrict__ T,
                                                 const unsigned short* __restrict__ xT,
                                                 float* __restrict__ out) {
    __shared__ __align__(16) unsigned short As[128 * 64];
    __shared__ __align__(16) unsigned short Bs[128 * 64];

    int bid = blockIdx.x;            // (b, mt, nt): nt fastest
    int b   = bid >> 7;
    int mt  = (bid >> 3) & 15;
    int nt  = bid & 7;
    int m0  = mt * 128, n0 = nt * 128;

    int t    = threadIdx.x;
    int lane = t & 63;
    int w    = t >> 6;
    int wr   = w >> 1, wc = w & 1;
    int lm   = lane & 15, quad = lane >> 4;

    const unsigned short* Ag = T + (size_t)m0 * N_;
    const unsigned short* Bg = xT + (size_t)(b * E_ + n0) * N_;

    // staging geometry: wave w covers rows [w*32, w*32+32) in 4 its of 8 rows
    int r8   = lane >> 3;                   // 0..7 row within group
    int gcol = ((lane & 7) ^ r8) * 8;       // xor-swizzled source col (ushorts)
    unsigned short* Al = As + w * 2048;     // + it*512 ; wave-uniform base
    unsigned short* Bl = Bs + w * 2048;

    f32x4 acc[4][4] = {};

    for (int kt = 0; kt < N_ / 64; ++kt) {
        int kbase = kt * 64;
        __syncthreads();                    // prev-iter LDS reads done
#pragma unroll
        for (int it = 0; it < 4; ++it) {
            int row = w * 32 + it * 8 + r8;
            async_copy16(Ag + (size_t)row * N_ + kbase + gcol, Al + it * 512);
            async_copy16(Bg + (size_t)row * N_ + kbase + gcol, Bl + it * 512);
        }
        __syncthreads();                    // drains vmcnt -> tiles visible
#pragma unroll
        for (int kh = 0; kh < 2; ++kh) {
            int cb = kh * 4 + quad;         // 16B col-block index 0..7
            bf16x8 af[4], bfr[4];
#pragma unroll
            for (int i = 0; i < 4; ++i) {
                int ra = wr * 64 + i * 16 + lm;
                int rb = wc * 64 + i * 16 + lm;
                af[i]  = *(const bf16x8*)(As + ra * 64 + ((cb ^ (ra & 7)) * 8));
                bfr[i] = *(const bf16x8*)(Bs + rb * 64 + ((cb ^ (rb & 7)) * 8));
            }
#pragma unroll
            for (int i = 0; i < 4; ++i)
#pragma unroll
                for (int jn = 0; jn < 4; ++jn)
                    acc[i][jn] = __builtin_amdgcn_mfma_f32_16x16x32_bf16(af[i], bfr[jn], acc[i][jn], 0, 0, 0);
        }
    }

    float* Og = out + ((size_t)(b * N_ + m0)) * E_ + n0;
#pragma unroll
    for (int i = 0; i < 4; ++i) {
#pragma unroll
        for (int jn = 0; jn < 4; ++jn) {
            int e = wc * 64 + jn * 16 + lm;
#pragma unroll
            for (int r = 0; r < 4; ++r) {
                int k = wr * 64 + i * 16 + quad * 4 + r;
                Og[(size_t)k * E_ + e] = acc[i][jn][r];
            }
        }
    }
}

// ---------------- fallback (ws too small): direct fp32 dot ------------------
__global__ __launch_bounds__(256) void naive_toep(const float* __restrict__ x,
                                                  const float* __restrict__ pos,
                                                  const float* __restrict__ zero,
                                                  const float* __restrict__ neg,
                                                  float* __restrict__ out) {
    int bid = blockIdx.x;
    int e   = (bid & 3) * 256 + threadIdx.x;
    int k   = (bid >> 2) & (N_ - 1);
    int b   = bid >> 13;
    float zv = zero[0];
    float acc = 0.f;
    const float* xb = x + (size_t)b * N_ * E_ + e;
    for (int j = 0; j < N_; ++j) {
        float c = (j < k) ? pos[k - j - 1] : (j == k) ? zv : neg[N_ - 1 - j + k];
        acc += c * xb[(size_t)j * E_];
    }
    out[((size_t)(b * N_ + k)) * E_ + e] = acc;
}

extern "C" void kernel_launch(void* const* d_in, const int* in_sizes, int n_in,
                              void* d_out, int out_size, void* d_ws, size_t ws_size,
                              hipStream_t stream) {
    const float* x    = (const float*)d_in[0];
    const float* pos  = (const float*)d_in[1];
    const float* zero = (const float*)d_in[2];
    const float* neg  = (const float*)d_in[3];
    float* out = (float*)d_out;

    const size_t needT = (size_t)N_ * N_ * sizeof(unsigned short);          // 8 MiB
    const size_t needX = (size_t)B_ * E_ * N_ * sizeof(unsigned short);     // 32 MiB
    if (ws_size >= needT + needX) {
        unsigned short* T  = (unsigned short*)d_ws;
        unsigned short* xT = (unsigned short*)d_ws + (size_t)N_ * N_;
        build_T<<<2048, 256, 0, stream>>>(pos, zero, neg, T);
        transpose_x<<<dim3(16, 32, 8), 256, 0, stream>>>(x, xT);
        gemm_toep<<<1024, 256, 0, stream>>>(T, xT, out);
    } else {
        naive_toep<<<65536, 256, 0, stream>>>(x, pos, zero, neg, out);
    }
}